// Round 1
// baseline (318.511 us; speedup 1.0000x reference)
//
#include <hip/hip_runtime.h>

// CTC batch loss (keras ctc_batch_cost semantics), B=256, T=512, C=256, U=64.
// One 64-lane wave per batch element. Lane l owns extended states 2l (blank)
// and 2l+1 (label l); lane 63 additionally owns state 128 (final blank) whose
// s-1 neighbor (state 127) is lane 63's own odd register -> no cross-lane op.
// Per time step: exactly one __shfl_up for alpha[2l-1]; register-rotating
// prefetch depth 7 hides HBM gather latency (511 steps = 7 * 73).

constexpr int B = 256, T = 512, C = 256, U = 64;
constexpr int BLANK = C - 1;
constexpr int PF = 7;                 // prefetch depth; 511 % 7 == 0
#define NEGF (-1e30f)
#define EPSF (1e-7f)

__device__ __forceinline__ float lae(float x, float y) {
    // logaddexp(x, y) = max + log1p(exp(min - max)); exact passthrough when
    // one side is ~-1e30 (exp underflows to 0).
    float m = fmaxf(x, y);
    float d = fminf(x, y) - m;
    return m + __logf(1.0f + __expf(d));
}

__global__ __launch_bounds__(64) void ctc_kernel(const int* __restrict__ y_true,
                                                 const float* __restrict__ y_pred,
                                                 float* __restrict__ out) {
    const int b = blockIdx.x;
    const int lane = threadIdx.x;                 // 0..63
    const int label = y_true[b * U + lane];
    const int label_prev = __shfl_up(label, 1);
    const bool skip_ok = (lane > 0) && (label != label_prev);

    const float* __restrict__ rowp = y_pred + (size_t)b * (T * C);

    // t = 0 init: alpha0[0] = lp(blank), alpha0[1] = lp(label0), rest NEG.
    float a_even = (lane == 0) ? __logf(rowp[BLANK] + EPSF) : NEGF;
    float a_odd  = (lane == 0) ? __logf(rowp[label] + EPSF) : NEGF;
    float a_top  = NEGF;                          // state 128 (valid on lane 63)

    // Prefetch rows t = 1 .. PF into rotating register buffers.
    float pf_lab[PF], pf_blk[PF];
#pragma unroll
    for (int i = 0; i < PF; ++i) {
        const float* r = rowp + (size_t)(1 + i) * C;
        pf_lab[i] = r[label];
        pf_blk[i] = r[BLANK];
    }

    for (int t0 = 1; t0 < T; t0 += PF) {          // 73 outer iterations
#pragma unroll
        for (int i = 0; i < PF; ++i) {            // slot i <-> step t = t0 + i
            const int t = t0 + i;
            const float plab = pf_lab[i];
            const float pblk = pf_blk[i];

            // Issue prefetch for step t + PF (clamped; tail loads hit L2).
            int tp = t + PF;
            tp = (tp < T) ? tp : (T - 1);
            const float* r = rowp + (size_t)tp * C;
            pf_lab[i] = r[label];
            pf_blk[i] = r[BLANK];

            const float lpb = __logf(pblk + EPSF);
            const float lpl = __logf(plab + EPSF);

            float prev_odd = __shfl_up(a_odd, 1); // alpha[2l - 1]
            if (lane == 0) prev_odd = NEGF;       // alpha[-1]
            const float skp = skip_ok ? prev_odd : NEGF;

            const float n_even = lae(a_even, prev_odd) + lpb;
            const float n_odd  = lae(lae(a_odd, a_even), skp) + lpl;
            const float n_top  = lae(a_top, a_odd) + lpb;  // meaningful on lane 63

            a_even = n_even;
            a_odd  = n_odd;
            a_top  = n_top;
        }
    }

    // loss = -logaddexp(alpha[S-1], alpha[S-2]) = -lae(state128, state127)
    if (lane == 63) out[b] = -lae(a_top, a_odd);
}

extern "C" void kernel_launch(void* const* d_in, const int* in_sizes, int n_in,
                              void* d_out, int out_size, void* d_ws, size_t ws_size,
                              hipStream_t stream) {
    const int* y_true  = (const int*)d_in[0];
    const float* y_pred = (const float*)d_in[1];
    float* out = (float*)d_out;
    hipLaunchKernelGGL(ctc_kernel, dim3(B), dim3(64), 0, stream,
                       y_true, y_pred, out);
}